// Round 3
// baseline (3557.911 us; speedup 1.0000x reference)
//
#include <hip/hip_runtime.h>
#include <cstdint>
#include <cstddef>

typedef __attribute__((ext_vector_type(8))) short short8;
typedef __attribute__((ext_vector_type(4))) short short4v;
typedef __attribute__((ext_vector_type(4))) float f32x4;

#define DEV __device__ __forceinline__

// Problem geometry (fixed by the reference)
constexpr int DD = 2048;           // D
constexpr int HHID = 8192;         // H
constexpr int BB = 4;              // B
constexpr int SS = 2048;           // S
constexpr size_t NX = (size_t)BB * SS * DD;   // 16,777,216
constexpr size_t NW = (size_t)DD * HHID;      // 16,777,216
constexpr size_t NH = (size_t)BB * SS * HHID; // 67,108,864

// Scratch layout (bytes)
constexpr size_t OFF_XH = 0;
constexpr size_t OFF_XL = OFF_XH + NX * 2;
constexpr size_t OFF_WH = OFF_XL + NX * 2;
constexpr size_t OFF_WL = OFF_WH + NW * 2;
constexpr size_t OFF_HH = OFF_WL + NW * 2;   // 128 MiB region
constexpr size_t OFF_HL = OFF_HH + NH * 2;   // 128 MiB region
constexpr size_t OFF_QH = OFF_HL + NH * 2;
constexpr size_t OFF_QL = OFF_QH + NX * 2;
constexpr size_t OFF_KH = OFF_QL + NX * 2;
constexpr size_t OFF_KL = OFF_KH + NX * 2;
constexpr size_t OFF_V  = OFF_KL + NX * 2;
constexpr size_t WS_TOTAL = OFF_V + NX * 2;  // ~570 MB
constexpr size_t OFF_ST = OFF_HH;            // fp32 scores^T
constexpr size_t OFF_PT = OFF_HL;            // bf16 probs^T

__device__ __align__(256) unsigned char g_ws[WS_TOTAL];

DEV unsigned char* wsbase(unsigned char* p) { return p ? p : (unsigned char*)g_ws; }
DEV short f2bf(float v) { __bf16 b = (__bf16)v; return __builtin_bit_cast(short, b); }
DEV float bf2f(short s) { return (float)__builtin_bit_cast(__bf16, s); }

DEV void gl16(const short* g, short* l) {
  __builtin_amdgcn_global_load_lds((const __attribute__((address_space(1))) void*)g,
                                   (__attribute__((address_space(3))) void*)l, 16, 0, 0);
}

// ---------------------------------------------------------------------------
// split cast: fp32 -> (hi, lo) bf16
// ---------------------------------------------------------------------------
__global__ void split_cast_k(const float* __restrict__ x, unsigned char* wsb,
                             size_t oh, size_t ol, size_t n4) {
  unsigned char* ws = wsbase(wsb);
  short4v* OH = (short4v*)(ws + oh);
  short4v* OL = (short4v*)(ws + ol);
  const f32x4* X = (const f32x4*)x;
  for (size_t i = (size_t)blockIdx.x * blockDim.x + threadIdx.x; i < n4;
       i += (size_t)gridDim.x * blockDim.x) {
    const f32x4 v = X[i];
    short4v hs, ls;
#pragma unroll
    for (int e = 0; e < 4; ++e) {
      const short hb = f2bf(v[e]);
      hs[e] = hb;
      ls[e] = f2bf(v[e] - bf2f(hb));
    }
    OH[i] = hs;
    OL[i] = ls;
  }
}

// ---------------------------------------------------------------------------
// transpose + (split-)cast: src R x C fp32 -> out C x R bf16 hi[/lo]
// ---------------------------------------------------------------------------
__global__ void transpose_cast_k(const float* __restrict__ src, unsigned char* wsb,
                                 size_t oh, size_t ol, int R, int C, int do_split) {
  __shared__ float t[32][33];
  unsigned char* ws = wsbase(wsb);
  short* OH = (short*)(ws + oh);
  short* OL = (short*)(ws + ol);
  const int c0 = blockIdx.x << 5, r0 = blockIdx.y << 5;
  const int x = threadIdx.x, y = threadIdx.y;
#pragma unroll
  for (int i = 0; i < 4; ++i) {
    const int rr = y + (i << 3);
    t[rr][x] = src[(size_t)(r0 + rr) * C + c0 + x];
  }
  __syncthreads();
#pragma unroll
  for (int i = 0; i < 4; ++i) {
    const int oc = y + (i << 3);
    const float v = t[x][oc];
    const size_t o = (size_t)(c0 + oc) * R + r0 + x;
    const short hb = f2bf(v);
    OH[o] = hb;
    if (do_split) OL[o] = f2bf(v - bf2f(hb));
  }
}

// ---------------------------------------------------------------------------
// 256x256-tile 8-wave deep-pipelined GEMM.
// A triple-buffered, B double-buffered in LDS (160 KiB total).
// Per K-tile: 4 phases; A(t+2) issued at phases 0-1, B(t+2) at phases 2-3,
// single counted vmcnt(8) at phase 3 (never 0 in steady state).
// C[m][n] = sum_k A[m][k] * BT[n][k].  NAB=1: plain bf16, BK=64.
// NAB=2: split hi/lo bf16 (3 MFMA terms), BK=32.
// STORE: 0 split-bf16 out (LDS-bounce), 1 bf16 out (LDS-bounce),
//        2 fp32 transposed scratch (f32x4), 3 fp32 optr direct.
// ---------------------------------------------------------------------------
constexpr int CH = 8192;        // shorts per 16KB chunk

template <int NAB>
DEV short8 read_frag(const short* base, int row, int s, int fg) {
  if constexpr (NAB == 1) {
    return *(const short8*)&base[row * 64 + ((((s << 2) | fg) ^ (row & 7)) << 3)];
  } else {
    return *(const short8*)&base[s * CH + row * 32 + ((fg ^ ((row >> 1) & 3)) << 3)];
  }
}

template <int NAB, int P>
DEV void mfma_cluster(f32x4 (&acc)[8][4], short8 (&av)[2][2], short8 (&bfr)[4][2]) {
  if constexpr (NAB == 1) {
#pragma unroll
    for (int s = 0; s < 2; ++s)
#pragma unroll
      for (int i2 = 0; i2 < 2; ++i2)
#pragma unroll
        for (int j = 0; j < 4; ++j)
          acc[2 * P + i2][j] = __builtin_amdgcn_mfma_f32_16x16x32_bf16(
              av[i2][s], bfr[j][s], acc[2 * P + i2][j], 0, 0, 0);
  } else {
#pragma unroll
    for (int i2 = 0; i2 < 2; ++i2)
#pragma unroll
      for (int j = 0; j < 4; ++j)
        acc[2 * P + i2][j] = __builtin_amdgcn_mfma_f32_16x16x32_bf16(
            av[i2][0], bfr[j][0], acc[2 * P + i2][j], 0, 0, 0);
#pragma unroll
    for (int i2 = 0; i2 < 2; ++i2)
#pragma unroll
      for (int j = 0; j < 4; ++j)
        acc[2 * P + i2][j] = __builtin_amdgcn_mfma_f32_16x16x32_bf16(
            av[i2][0], bfr[j][1], acc[2 * P + i2][j], 0, 0, 0);
#pragma unroll
    for (int i2 = 0; i2 < 2; ++i2)
#pragma unroll
      for (int j = 0; j < 4; ++j)
        acc[2 * P + i2][j] = __builtin_amdgcn_mfma_f32_16x16x32_bf16(
            av[i2][1], bfr[j][0], acc[2 * P + i2][j], 0, 0, 0);
  }
}

#define READ_AV(P)                                                       \
  av[0][0] = read_frag<NAB>(aBase, wm + (2 * (P)) * 16 + fr, 0, fg);     \
  av[0][1] = read_frag<NAB>(aBase, wm + (2 * (P)) * 16 + fr, 1, fg);     \
  av[1][0] = read_frag<NAB>(aBase, wm + (2 * (P) + 1) * 16 + fr, 0, fg); \
  av[1][1] = read_frag<NAB>(aBase, wm + (2 * (P) + 1) * 16 + fr, 1, fg);

#define PHASE_TAIL(P)                                       \
  __builtin_amdgcn_s_barrier();                             \
  asm volatile("s_waitcnt lgkmcnt(0)" ::: "memory");        \
  __builtin_amdgcn_s_setprio(1);                            \
  mfma_cluster<NAB, P>(acc, av, bfr);                       \
  __builtin_amdgcn_s_setprio(0);                            \
  __builtin_amdgcn_s_barrier();

template <int NAB, bool RELU, int STORE>
__launch_bounds__(512, 2)
__global__ void gemm8_k(unsigned char* wsb,
                        size_t aoff0, size_t aoff1, size_t boff0, size_t boff1,
                        const float* __restrict__ bias,
                        size_t ooff0, size_t ooff1, float* __restrict__ optr,
                        int M, int N, int K, int gx, int gxy) {
  constexpr int BK = (NAB == 2) ? 32 : 64;
  // LDS: A slots 0,1,2 at {0,2CH,4CH}; B slots at {6CH, 8CH}. 10*CH*2B = 160 KiB.
  __shared__ alignas(16) short lds[10 * CH];

  unsigned char* ws = wsbase(wsb);
  const int tid = threadIdx.x;
  const int lane = tid & 63;
  const int wave = tid >> 6;
  const int wm = (wave >> 2) << 7;   // 0 / 128
  const int wn = (wave & 3) << 6;    // 0 / 64 / 128 / 192

  // bijective XCD swizzle (all grids are multiples of 8)
  const int nwg = gridDim.x;
  const int q8 = nwg >> 3;
  const int id = (blockIdx.x & 7) * q8 + (blockIdx.x >> 3);
  const int bz = id / gxy;
  const int rem = id - bz * gxy;
  const int by = rem / gx;
  const int bx = rem - by * gx;
  const int brow = by << 8;
  const int bcol = bx << 8;

  const size_t batchA = (size_t)bz * M * K;
  const size_t batchB = (size_t)bz * N * K;
  const short* A0 = (const short*)(ws + aoff0) + batchA;
  const short* A1 = (const short*)(ws + aoff1) + batchA;
  const short* B0g = (const short*)(ws + boff0) + batchB;
  const short* B1g = (const short*)(ws + boff1) + batchB;

  // per-thread staging source offsets (granule-swizzled), [chunk q][half]
  size_t aSrc[2][2], bSrc[2][2];
#pragma unroll
  for (int h = 0; h < 2; ++h) {
    const int G = tid + h * 512;
    if constexpr (NAB == 1) {
      const int r = G >> 3, c = G & 7;
#pragma unroll
      for (int qq = 0; qq < 2; ++qq) {
        aSrc[qq][h] = (size_t)(brow + qq * 128 + r) * K + (size_t)((c ^ (r & 7)) << 3);
        bSrc[qq][h] = (size_t)(bcol + qq * 128 + r) * K + (size_t)((c ^ (r & 7)) << 3);
      }
    } else {
      const int r = G >> 2, c = G & 3;
      const size_t sw = (size_t)((c ^ ((r >> 1) & 3)) << 3);
      aSrc[0][h] = aSrc[1][h] = (size_t)(brow + r) * K + sw;
      bSrc[0][h] = bSrc[1][h] = (size_t)(bcol + r) * K + sw;
    }
  }
  const int ldst0 = tid << 3;   // dest short offset within chunk

  auto issueA = [&](int slot, int qq, int tt) {
    short* dst = &lds[slot + qq * CH];
    const short* sp = (NAB == 2) ? (qq ? A1 : A0) : A0;
    const size_t ka = (size_t)tt * BK;
    gl16(sp + aSrc[qq][0] + ka, dst + ldst0);
    gl16(sp + aSrc[qq][1] + ka, dst + ldst0 + CH / 2);
  };
  auto issueB = [&](int slot, int qq, int tt) {
    short* dst = &lds[slot + qq * CH];
    const short* sp = (NAB == 2) ? (qq ? B1g : B0g) : B0g;
    const size_t ka = (size_t)tt * BK;
    gl16(sp + bSrc[qq][0] + ka, dst + ldst0);
    gl16(sp + bSrc[qq][1] + ka, dst + ldst0 + CH / 2);
  };

  const int nt = K / BK;
  const int fr = lane & 15;
  const int fg = lane >> 4;

  f32x4 acc[8][4] = {};

  // prologue: A(0)->slot0, B(0)->Bslot0, A(1)->slot1, B(1)->Bslot1
  issueA(0, 0, 0); issueA(0, 1, 0);
  issueB(6 * CH, 0, 0); issueB(6 * CH, 1, 0);
  if (nt > 1) {
    issueA(2 * CH, 0, 1); issueA(2 * CH, 1, 1);
    issueB(8 * CH, 0, 1); issueB(8 * CH, 1, 1);
    asm volatile("s_waitcnt vmcnt(8)" ::: "memory");
  } else {
    asm volatile("s_waitcnt vmcnt(0)" ::: "memory");
  }
  __builtin_amdgcn_s_barrier();

  for (int t = 0; t < nt; ++t) {
    const int sA  = (t % 3) * (2 * CH);
    const int sA2 = ((t + 2) % 3) * (2 * CH);
    const int sB  = 6 * CH + (t & 1) * (2 * CH);
    const short* aBase = &lds[sA];
    const short* bBase = &lds[sB];
    const bool pf = (t + 2 < nt);
    short8 av[2][2], bfr[4][2];

    // ---- phase 0: issue A(t+2) chunk0; read all B frags + A rows 0-1 ----
    if (pf) issueA(sA2, 0, t + 2);
#pragma unroll
    for (int j = 0; j < 4; ++j) {
      bfr[j][0] = read_frag<NAB>(bBase, wn + j * 16 + fr, 0, fg);
      bfr[j][1] = read_frag<NAB>(bBase, wn + j * 16 + fr, 1, fg);
    }
    READ_AV(0);
    PHASE_TAIL(0);

    // ---- phase 1: issue A(t+2) chunk1; A rows 2-3 ----
    if (pf) issueA(sA2, 1, t + 2);
    READ_AV(1);
    PHASE_TAIL(1);

    // ---- phase 2: issue B(t+2) chunk0 (B(t) dead after phase 0); A rows 4-5 ----
    if (pf) issueB(sB, 0, t + 2);
    READ_AV(2);
    PHASE_TAIL(2);

    // ---- phase 3: issue B(t+2) chunk1; A rows 6-7; counted vmcnt ----
    if (pf) issueB(sB, 1, t + 2);
    READ_AV(3);
    if (pf) {
      asm volatile("s_waitcnt vmcnt(8)" ::: "memory");
    } else {
      asm volatile("s_waitcnt vmcnt(0)" ::: "memory");
    }
    PHASE_TAIL(3);
  }

  // ---- epilogue ----
  const int fq4 = (lane >> 4) << 2;
  if constexpr (STORE == 0 || STORE == 1) {
    // LDS-bounce: stage 256x256 bf16 tile (stride 264 shorts), store dwordx4.
    short* Oh = (short*)(ws + ooff0);
    short* Ol = (short*)(ws + ooff1);
    constexpr int ROUNDS = (STORE == 0) ? 2 : 1;
#pragma unroll
    for (int rd = 0; rd < ROUNDS; ++rd) {
      __builtin_amdgcn_s_barrier();
#pragma unroll
      for (int i = 0; i < 8; ++i) {
        const int rl = wm + i * 16 + fq4;
#pragma unroll
        for (int j = 0; j < 4; ++j) {
          const int cl = wn + j * 16 + fr;
          const float bv = bias ? bias[bcol + cl] : 0.0f;
#pragma unroll
          for (int e = 0; e < 4; ++e) {
            float u = acc[i][j][e] + bv;
            if constexpr (RELU) u = fmaxf(u, 0.0f);
            short v;
            if (rd == 0) {
              v = f2bf(u);
            } else {
              const short hb = f2bf(u);
              v = f2bf(u - bf2f(hb));
            }
            lds[(rl + e) * 264 + cl] = v;
          }
        }
      }
      __builtin_amdgcn_s_barrier();
      short* gout = (rd == 0) ? Oh : Ol;
#pragma unroll
      for (int gi = 0; gi < 16; ++gi) {
        const int g = gi * 512 + tid;
        const int row = g >> 5, cg = g & 31;
        const short8 v = *(const short8*)&lds[row * 264 + cg * 8];
        *(short8*)&gout[(size_t)(brow + row) * N + bcol + cg * 8] = v;
      }
    }
  } else if constexpr (STORE == 2) {
    float* Of = (float*)(ws + ooff0) + (size_t)bz * M * N;
#pragma unroll
    for (int i = 0; i < 8; ++i) {
      const int r = brow + wm + i * 16 + fq4;
#pragma unroll
      for (int j = 0; j < 4; ++j) {
        const int c = bcol + wn + j * 16 + fr;
        *(f32x4*)&Of[(size_t)c * M + r] = acc[i][j];   // transposed: ST[n][m..m+3]
      }
    }
  } else {
    float* Op = optr + (size_t)bz * M * N;
#pragma unroll
    for (int i = 0; i < 8; ++i) {
      const int r = brow + wm + i * 16 + fq4;
#pragma unroll
      for (int j = 0; j < 4; ++j) {
        const int c = bcol + wn + j * 16 + fr;
#pragma unroll
        for (int e = 0; e < 4; ++e)
          Op[(size_t)(r + e) * N + c] = acc[i][j][e];
      }
    }
  }
}

// ---------------------------------------------------------------------------
// row softmax over ST rows (axis-1 softmax of scores), output bf16 probs^T
// ---------------------------------------------------------------------------
__launch_bounds__(256)
__global__ void softmax_rows_k(unsigned char* wsb, size_t st, size_t pt) {
  constexpr int S = 2048;
  unsigned char* ws = wsbase(wsb);
  const f32x4* row = (const f32x4*)((const float*)(ws + st) + (size_t)blockIdx.x * S);
  short4v* out = (short4v*)((short*)(ws + pt) + (size_t)blockIdx.x * S);
  const int tid = threadIdx.x, lane = tid & 63, wv = tid >> 6;
  const f32x4 a = row[tid];
  const f32x4 b = row[tid + 256];
  float m = fmaxf(fmaxf(fmaxf(a[0], a[1]), fmaxf(a[2], a[3])),
                  fmaxf(fmaxf(b[0], b[1]), fmaxf(b[2], b[3])));
#pragma unroll
  for (int o = 32; o; o >>= 1) m = fmaxf(m, __shfl_xor(m, o));
  __shared__ float rb[8];
  if (lane == 0) rb[wv] = m;
  __syncthreads();
  m = fmaxf(fmaxf(rb[0], rb[1]), fmaxf(rb[2], rb[3]));
  float e[8];
  float s = 0.0f;
#pragma unroll
  for (int q = 0; q < 4; ++q) { e[q] = expf(a[q] - m); s += e[q]; }
#pragma unroll
  for (int q = 0; q < 4; ++q) { e[4 + q] = expf(b[q] - m); s += e[4 + q]; }
#pragma unroll
  for (int o = 32; o; o >>= 1) s += __shfl_xor(s, o);
  if (lane == 0) rb[4 + wv] = s;
  __syncthreads();
  s = rb[4] + rb[5] + rb[6] + rb[7];
  const float inv = 1.0f / s;
  short4v o1, o2;
#pragma unroll
  for (int q = 0; q < 4; ++q) { o1[q] = f2bf(e[q] * inv); o2[q] = f2bf(e[4 + q] * inv); }
  out[tid] = o1;
  out[tid + 256] = o2;
}

// ---------------------------------------------------------------------------
extern "C" void kernel_launch(void* const* d_in, const int* in_sizes, int n_in,
                              void* d_out, int out_size, void* d_ws, size_t ws_size,
                              hipStream_t stream) {
  const float* x   = (const float*)d_in[0];
  const float* qw1 = (const float*)d_in[1];
  const float* qb1 = (const float*)d_in[2];
  const float* qw2 = (const float*)d_in[3];
  const float* qb2 = (const float*)d_in[4];
  const float* kw1 = (const float*)d_in[5];
  const float* kb1 = (const float*)d_in[6];
  const float* kw2 = (const float*)d_in[7];
  const float* kb2 = (const float*)d_in[8];
  const float* vw1 = (const float*)d_in[9];
  const float* vb1 = (const float*)d_in[10];
  const float* vw2 = (const float*)d_in[11];
  const float* vb2 = (const float*)d_in[12];
  float* out = (float*)d_out;
  unsigned char* wsb = (ws_size >= WS_TOTAL) ? (unsigned char*)d_ws : nullptr;

  const int M = BB * SS;  // 8192
  dim3 blk(512);
  dim3 tb(32, 8);

  // x -> hi/lo bf16
  split_cast_k<<<4096, 256, 0, stream>>>(x, wsb, OFF_XH, OFF_XL, NX / 4);

  // ---- Q path (split precision) ----
  transpose_cast_k<<<dim3(HHID / 32, DD / 32), tb, 0, stream>>>(qw1, wsb, OFF_WH, OFF_WL, DD, HHID, 1);
  gemm8_k<2, true, 0><<<1024, blk, 0, stream>>>(
      wsb, OFF_XH, OFF_XL, OFF_WH, OFF_WL, qb1, OFF_HH, OFF_HL, nullptr, M, HHID, DD, 32, 1024);
  transpose_cast_k<<<dim3(DD / 32, HHID / 32), tb, 0, stream>>>(qw2, wsb, OFF_WH, OFF_WL, HHID, DD, 1);
  gemm8_k<2, false, 0><<<256, blk, 0, stream>>>(
      wsb, OFF_HH, OFF_HL, OFF_WH, OFF_WL, qb2, OFF_QH, OFF_QL, nullptr, M, DD, HHID, 8, 256);

  // ---- K path (split precision) ----
  transpose_cast_k<<<dim3(HHID / 32, DD / 32), tb, 0, stream>>>(kw1, wsb, OFF_WH, OFF_WL, DD, HHID, 1);
  gemm8_k<2, true, 0><<<1024, blk, 0, stream>>>(
      wsb, OFF_XH, OFF_XL, OFF_WH, OFF_WL, kb1, OFF_HH, OFF_HL, nullptr, M, HHID, DD, 32, 1024);
  transpose_cast_k<<<dim3(DD / 32, HHID / 32), tb, 0, stream>>>(kw2, wsb, OFF_WH, OFF_WL, HHID, DD, 1);
  gemm8_k<2, false, 0><<<256, blk, 0, stream>>>(
      wsb, OFF_HH, OFF_HL, OFF_WH, OFF_WL, kb2, OFF_KH, OFF_KL, nullptr, M, DD, HHID, 8, 256);

  // ---- V path (plain bf16) ----
  transpose_cast_k<<<dim3(HHID / 32, DD / 32), tb, 0, stream>>>(vw1, wsb, OFF_WH, OFF_WL, DD, HHID, 0);
  gemm8_k<1, true, 1><<<1024, blk, 0, stream>>>(
      wsb, OFF_XH, 0, OFF_WH, 0, vb1, OFF_HH, 0, nullptr, M, HHID, DD, 32, 1024);
  transpose_cast_k<<<dim3(DD / 32, HHID / 32), tb, 0, stream>>>(vw2, wsb, OFF_WH, OFF_WL, HHID, DD, 0);
  gemm8_k<1, false, 1><<<256, blk, 0, stream>>>(
      wsb, OFF_HH, 0, OFF_WH, 0, vb2, OFF_V, 0, nullptr, M, DD, HHID, 8, 256);

  // ---- scores^T = (Q K^T)^T per batch, split precision, fp32 ----
  gemm8_k<2, false, 2><<<256, blk, 0, stream>>>(
      wsb, OFF_QH, OFF_QL, OFF_KH, OFF_KL, nullptr, OFF_ST, 0, nullptr, SS, SS, DD, 8, 64);

  // ---- softmax over axis 1 == row softmax of ST; writes bf16 probs^T ----
  softmax_rows_k<<<BB * SS, 256, 0, stream>>>(wsb, OFF_ST, OFF_PT);

  // ---- out = V @ probs  (B^T = probs^T), fp32 to d_out ----
  gemm8_k<1, false, 3><<<256, blk, 0, stream>>>(
      wsb, OFF_V, 0, OFF_PT, 0, nullptr, 0, 0, out, SS, SS, DD, 8, 64);
}

// Round 4
// 3501.550 us; speedup vs baseline: 1.0161x; 1.0161x over previous
//
#include <hip/hip_runtime.h>
#include <cstdint>
#include <cstddef>

typedef __attribute__((ext_vector_type(8))) short short8;
typedef __attribute__((ext_vector_type(4))) short short4v;
typedef __attribute__((ext_vector_type(4))) float f32x4;

#define DEV __device__ __forceinline__

// Problem geometry (fixed by the reference)
constexpr int DD = 2048;           // D
constexpr int HHID = 8192;         // H
constexpr int BB = 4;              // B
constexpr int SS = 2048;           // S
constexpr size_t NX = (size_t)BB * SS * DD;   // 16,777,216
constexpr size_t NW = (size_t)DD * HHID;      // 16,777,216
constexpr size_t NH = (size_t)BB * SS * HHID; // 67,108,864

// Scratch layout (bytes)
constexpr size_t OFF_XH = 0;
constexpr size_t OFF_XL = OFF_XH + NX * 2;
constexpr size_t OFF_WH = OFF_XL + NX * 2;
constexpr size_t OFF_WL = OFF_WH + NW * 2;
constexpr size_t OFF_HH = OFF_WL + NW * 2;   // 128 MiB region
constexpr size_t OFF_HL = OFF_HH + NH * 2;   // 128 MiB region
constexpr size_t OFF_QH = OFF_HL + NH * 2;
constexpr size_t OFF_QL = OFF_QH + NX * 2;
constexpr size_t OFF_KH = OFF_QL + NX * 2;
constexpr size_t OFF_KL = OFF_KH + NX * 2;
constexpr size_t OFF_V  = OFF_KL + NX * 2;
constexpr size_t WS_TOTAL = OFF_V + NX * 2;  // ~570 MB
constexpr size_t OFF_ST = OFF_HH;            // fp32 scores^T
constexpr size_t OFF_PT = OFF_HL;            // bf16 probs^T

__device__ __align__(256) unsigned char g_ws[WS_TOTAL];

DEV unsigned char* wsbase(unsigned char* p) { return p ? p : (unsigned char*)g_ws; }
DEV short f2bf(float v) { __bf16 b = (__bf16)v; return __builtin_bit_cast(short, b); }
DEV float bf2f(short s) { return (float)__builtin_bit_cast(__bf16, s); }

DEV void gl16(const short* g, short* l) {
  __builtin_amdgcn_global_load_lds((const __attribute__((address_space(1))) void*)g,
                                   (__attribute__((address_space(3))) void*)l, 16, 0, 0);
}

// ---------------------------------------------------------------------------
// split cast: fp32 -> (hi, lo) bf16
// ---------------------------------------------------------------------------
__global__ void split_cast_k(const float* __restrict__ x, unsigned char* wsb,
                             size_t oh, size_t ol, size_t n4) {
  unsigned char* ws = wsbase(wsb);
  short4v* OH = (short4v*)(ws + oh);
  short4v* OL = (short4v*)(ws + ol);
  const f32x4* X = (const f32x4*)x;
  for (size_t i = (size_t)blockIdx.x * blockDim.x + threadIdx.x; i < n4;
       i += (size_t)gridDim.x * blockDim.x) {
    const f32x4 v = X[i];
    short4v hs, ls;
#pragma unroll
    for (int e = 0; e < 4; ++e) {
      const short hb = f2bf(v[e]);
      hs[e] = hb;
      ls[e] = f2bf(v[e] - bf2f(hb));
    }
    OH[i] = hs;
    OL[i] = ls;
  }
}

// ---------------------------------------------------------------------------
// transpose + (split-)cast: src R x C fp32 -> out C x R bf16 hi[/lo]
// ---------------------------------------------------------------------------
__global__ void transpose_cast_k(const float* __restrict__ src, unsigned char* wsb,
                                 size_t oh, size_t ol, int R, int C, int do_split) {
  __shared__ float t[32][33];
  unsigned char* ws = wsbase(wsb);
  short* OH = (short*)(ws + oh);
  short* OL = (short*)(ws + ol);
  const int c0 = blockIdx.x << 5, r0 = blockIdx.y << 5;
  const int x = threadIdx.x, y = threadIdx.y;
#pragma unroll
  for (int i = 0; i < 4; ++i) {
    const int rr = y + (i << 3);
    t[rr][x] = src[(size_t)(r0 + rr) * C + c0 + x];
  }
  __syncthreads();
#pragma unroll
  for (int i = 0; i < 4; ++i) {
    const int oc = y + (i << 3);
    const float v = t[x][oc];
    const size_t o = (size_t)(c0 + oc) * R + r0 + x;
    const short hb = f2bf(v);
    OH[o] = hb;
    if (do_split) OL[o] = f2bf(v - bf2f(hb));
  }
}

// ---------------------------------------------------------------------------
// 256x256-tile 8-wave pipelined GEMM, 2 phases per K-tile.
// A triple-buffered, B double-buffered in LDS (160 KiB total).
// Phase A: issue A(t+2) staging; ds_read B frags + A rows 0-3; MFMA half 0
//          (compiler-interleaved reads/MFMA, no explicit lgkm drain); barrier.
// Phase B: issue B(t+2) staging (B(t) consumed in phase A); ds_read A rows
//          4-7; MFMA half 1; counted vmcnt(8); barrier.
// C[m][n] = sum_k A[m][k] * BT[n][k].  NAB=1: plain bf16, BK=64.
// NAB=2: split hi/lo bf16 (3 MFMA terms), BK=32.
// STORE: 0 split-bf16 out (LDS-bounce), 1 bf16 out (LDS-bounce),
//        2 fp32 transposed scratch (LDS-transpose bounce, coalesced),
//        3 fp32 optr (LDS-bounce, coalesced).
// ---------------------------------------------------------------------------
constexpr int CH = 8192;        // shorts per 16KB chunk

template <int NAB>
DEV short8 read_frag(const short* base, int row, int s, int fg) {
  if constexpr (NAB == 1) {
    return *(const short8*)&base[row * 64 + ((((s << 2) | fg) ^ (row & 7)) << 3)];
  } else {
    return *(const short8*)&base[s * CH + row * 32 + ((fg ^ ((row >> 1) & 3)) << 3)];
  }
}

DEV f32x4 mfma16(short8 a, short8 b, f32x4 c) {
  return __builtin_amdgcn_mfma_f32_16x16x32_bf16(a, b, c, 0, 0, 0);
}

template <int NAB>
DEV void read_half(const short* aBase, int base_row, int fr, int fg, short8 (&av)[4][2]) {
#pragma unroll
  for (int i = 0; i < 4; ++i) {
    const int row = base_row + i * 16 + fr;
    av[i][0] = read_frag<NAB>(aBase, row, 0, fg);
    av[i][1] = read_frag<NAB>(aBase, row, 1, fg);
  }
}

template <int NAB, int H>
DEV void mfma_half(f32x4 (&acc)[8][4], const short8 (&av)[4][2], const short8 (&bfr)[4][2]) {
#pragma unroll
  for (int i = 0; i < 4; ++i)
#pragma unroll
    for (int j = 0; j < 4; ++j) {
      if constexpr (NAB == 1) {
        acc[H * 4 + i][j] = mfma16(av[i][0], bfr[j][0], acc[H * 4 + i][j]);
        acc[H * 4 + i][j] = mfma16(av[i][1], bfr[j][1], acc[H * 4 + i][j]);
      } else {
        acc[H * 4 + i][j] = mfma16(av[i][0], bfr[j][0], acc[H * 4 + i][j]);
        acc[H * 4 + i][j] = mfma16(av[i][0], bfr[j][1], acc[H * 4 + i][j]);
        acc[H * 4 + i][j] = mfma16(av[i][1], bfr[j][0], acc[H * 4 + i][j]);
      }
    }
}

template <int NAB, bool RELU, int STORE>
__launch_bounds__(512, 2)
__global__ void gemm8_k(unsigned char* wsb,
                        size_t aoff0, size_t aoff1, size_t boff0, size_t boff1,
                        const float* __restrict__ bias,
                        size_t ooff0, size_t ooff1, float* __restrict__ optr,
                        int M, int N, int K, int gx, int gxy) {
  constexpr int BK = (NAB == 2) ? 32 : 64;
  // LDS: A slots 0,1,2 at {0,2CH,4CH}; B slots at {6CH, 8CH}. 10*CH*2B = 160 KiB.
  __shared__ alignas(16) short lds[10 * CH];

  unsigned char* ws = wsbase(wsb);
  const int tid = threadIdx.x;
  const int lane = tid & 63;
  const int wave = tid >> 6;
  const int wm = (wave >> 2) << 7;   // 0 / 128
  const int wn = (wave & 3) << 6;    // 0 / 64 / 128 / 192

  // bijective XCD swizzle (all grids are multiples of 8)
  const int nwg = gridDim.x;
  const int q8 = nwg >> 3;
  const int id = (blockIdx.x & 7) * q8 + (blockIdx.x >> 3);
  const int bz = id / gxy;
  const int rem = id - bz * gxy;
  const int by = rem / gx;
  const int bx = rem - by * gx;
  const int brow = by << 8;
  const int bcol = bx << 8;

  const size_t batchA = (size_t)bz * M * K;
  const size_t batchB = (size_t)bz * N * K;
  const short* A0 = (const short*)(ws + aoff0) + batchA;
  const short* A1 = (const short*)(ws + aoff1) + batchA;
  const short* B0g = (const short*)(ws + boff0) + batchB;
  const short* B1g = (const short*)(ws + boff1) + batchB;

  // per-thread staging source offsets (granule-swizzled), [chunk q][half]
  size_t aSrc[2][2], bSrc[2][2];
#pragma unroll
  for (int h = 0; h < 2; ++h) {
    const int G = tid + h * 512;
    if constexpr (NAB == 1) {
      const int r = G >> 3, c = G & 7;
#pragma unroll
      for (int qq = 0; qq < 2; ++qq) {
        aSrc[qq][h] = (size_t)(brow + qq * 128 + r) * K + (size_t)((c ^ (r & 7)) << 3);
        bSrc[qq][h] = (size_t)(bcol + qq * 128 + r) * K + (size_t)((c ^ (r & 7)) << 3);
      }
    } else {
      const int r = G >> 2, c = G & 3;
      const size_t sw = (size_t)((c ^ ((r >> 1) & 3)) << 3);
      aSrc[0][h] = aSrc[1][h] = (size_t)(brow + r) * K + sw;
      bSrc[0][h] = bSrc[1][h] = (size_t)(bcol + r) * K + sw;
    }
  }
  const int ldst0 = tid << 3;   // dest short offset within chunk

  auto issueA = [&](int slot, int qq, int tt) {
    short* dst = &lds[slot + qq * CH];
    const short* sp = (NAB == 2) ? (qq ? A1 : A0) : A0;
    const size_t ka = (size_t)tt * BK;
    gl16(sp + aSrc[qq][0] + ka, dst + ldst0);
    gl16(sp + aSrc[qq][1] + ka, dst + ldst0 + CH / 2);
  };
  auto issueB = [&](int slot, int qq, int tt) {
    short* dst = &lds[slot + qq * CH];
    const short* sp = (NAB == 2) ? (qq ? B1g : B0g) : B0g;
    const size_t ka = (size_t)tt * BK;
    gl16(sp + bSrc[qq][0] + ka, dst + ldst0);
    gl16(sp + bSrc[qq][1] + ka, dst + ldst0 + CH / 2);
  };

  const int nt = K / BK;
  const int fr = lane & 15;
  const int fg = lane >> 4;

  f32x4 acc[8][4] = {};

  // prologue: A(0)->slot0, B(0)->Bslot0, A(1)->slot1, B(1)->Bslot1
  issueA(0, 0, 0); issueA(0, 1, 0);
  issueB(6 * CH, 0, 0); issueB(6 * CH, 1, 0);
  if (nt > 1) {
    issueA(2 * CH, 0, 1); issueA(2 * CH, 1, 1);
    issueB(8 * CH, 0, 1); issueB(8 * CH, 1, 1);
    asm volatile("s_waitcnt vmcnt(8)" ::: "memory");
  } else {
    asm volatile("s_waitcnt vmcnt(0)" ::: "memory");
  }
  __builtin_amdgcn_s_barrier();

  for (int t = 0; t < nt; ++t) {
    const short* aBase = &lds[(t % 3) * (2 * CH)];
    const short* bBase = &lds[6 * CH + (t & 1) * (2 * CH)];
    const int sA2 = ((t + 2) % 3) * (2 * CH);
    const int sB  = 6 * CH + (t & 1) * (2 * CH);
    const bool pf = (t + 2 < nt);
    short8 bfr[4][2], av[4][2];

    // ---- phase A: stage A(t+2); read B frags + A rows 0-3; MFMA half 0 ----
    if (pf) { issueA(sA2, 0, t + 2); issueA(sA2, 1, t + 2); }
#pragma unroll
    for (int j = 0; j < 4; ++j) {
      bfr[j][0] = read_frag<NAB>(bBase, wn + j * 16 + fr, 0, fg);
      bfr[j][1] = read_frag<NAB>(bBase, wn + j * 16 + fr, 1, fg);
    }
    read_half<NAB>(aBase, wm, fr, fg, av);
    __builtin_amdgcn_s_setprio(1);
    mfma_half<NAB, 0>(acc, av, bfr);
    __builtin_amdgcn_s_setprio(0);
    __builtin_amdgcn_s_barrier();

    // ---- phase B: stage B(t+2) (B(t) fully consumed); A rows 4-7; MFMA half 1 ----
    asm volatile("" ::: "memory");
    if (pf) { issueB(sB, 0, t + 2); issueB(sB, 1, t + 2); }
    read_half<NAB>(aBase, wm + 64, fr, fg, av);
    __builtin_amdgcn_s_setprio(1);
    mfma_half<NAB, 1>(acc, av, bfr);
    __builtin_amdgcn_s_setprio(0);
    if (pf) {
      asm volatile("s_waitcnt vmcnt(8)" ::: "memory");
    } else {
      asm volatile("s_waitcnt vmcnt(0)" ::: "memory");
    }
    __builtin_amdgcn_s_barrier();
  }

  // ---- epilogue ----
  const int fq4 = (lane >> 4) << 2;
  if constexpr (STORE == 0 || STORE == 1) {
    // LDS-bounce: stage 256x256 bf16 tile (stride 264 shorts), store dwordx4.
    short* Oh = (short*)(ws + ooff0);
    short* Ol = (short*)(ws + ooff1);
    constexpr int ROUNDS = (STORE == 0) ? 2 : 1;
#pragma unroll
    for (int rd = 0; rd < ROUNDS; ++rd) {
      __builtin_amdgcn_s_barrier();
#pragma unroll
      for (int i = 0; i < 8; ++i) {
        const int rl = wm + i * 16 + fq4;
#pragma unroll
        for (int j = 0; j < 4; ++j) {
          const int cl = wn + j * 16 + fr;
          const float bv = bias ? bias[bcol + cl] : 0.0f;
#pragma unroll
          for (int e = 0; e < 4; ++e) {
            float u = acc[i][j][e] + bv;
            if constexpr (RELU) u = fmaxf(u, 0.0f);
            short v;
            if (rd == 0) {
              v = f2bf(u);
            } else {
              const short hb = f2bf(u);
              v = f2bf(u - bf2f(hb));
            }
            lds[(rl + e) * 264 + cl] = v;
          }
        }
      }
      __builtin_amdgcn_s_barrier();
      short* gout = (rd == 0) ? Oh : Ol;
#pragma unroll
      for (int gi = 0; gi < 16; ++gi) {
        const int g = gi * 512 + tid;
        const int row = g >> 5, cg = g & 31;
        const short8 v = *(const short8*)&lds[row * 264 + cg * 8];
        *(short8*)&gout[(size_t)(brow + row) * N + bcol + cg * 8] = v;
      }
    }
  } else if constexpr (STORE == 2) {
    // transposed fp32 scratch: LDS-transpose bounce in 2 column-halves
    float* Of = (float*)(ws + ooff0) + (size_t)bz * M * N;
    float* ldsf = (float*)lds;
#pragma unroll
    for (int h = 0; h < 2; ++h) {
      __builtin_amdgcn_s_barrier();
      if ((wn & 128) == (h << 7)) {
#pragma unroll
        for (int i = 0; i < 8; ++i) {
          const int rl = wm + i * 16 + fq4;
#pragma unroll
          for (int j = 0; j < 4; ++j) {
            const int cp = (wn & 127) + j * 16 + fr;   // col within half
#pragma unroll
            for (int e = 0; e < 4; ++e)
              ldsf[cp * 258 + rl + e] = acc[i][j][e];
          }
        }
      }
      __builtin_amdgcn_s_barrier();
#pragma unroll
      for (int gi = 0; gi < 16; ++gi) {
        const int g = gi * 512 + tid;
        const int tr = g >> 6, tc4 = (g & 63) << 2;
        const f32x4 v = *(const f32x4*)&ldsf[tr * 258 + tc4];
        *(f32x4*)&Of[(size_t)(bcol + h * 128 + tr) * M + brow + tc4] = v;
      }
    }
  } else {
    // fp32 row-major out: LDS-bounce in 2 row-halves for coalesced stores
    float* Op = optr + (size_t)bz * M * N;
    float* ldsf = (float*)lds;
#pragma unroll
    for (int h = 0; h < 2; ++h) {
      __builtin_amdgcn_s_barrier();
      if ((wm & 128) == (h << 7)) {
#pragma unroll
        for (int i = 0; i < 8; ++i) {
          const int rp = (wm & 127) + i * 16 + fq4;   // row within half
#pragma unroll
          for (int j = 0; j < 4; ++j) {
            const int cl = wn + j * 16 + fr;
#pragma unroll
            for (int e = 0; e < 4; ++e)
              ldsf[(rp + e) * 258 + cl] = acc[i][j][e];
          }
        }
      }
      __builtin_amdgcn_s_barrier();
#pragma unroll
      for (int gi = 0; gi < 16; ++gi) {
        const int g = gi * 512 + tid;
        const int tr = g >> 6, tc4 = (g & 63) << 2;
        const f32x4 v = *(const f32x4*)&ldsf[tr * 258 + tc4];
        *(f32x4*)&Op[(size_t)(brow + h * 128 + tr) * N + bcol + tc4] = v;
      }
    }
  }
}

// ---------------------------------------------------------------------------
// row softmax over ST rows (axis-1 softmax of scores), output bf16 probs^T
// ---------------------------------------------------------------------------
__launch_bounds__(256)
__global__ void softmax_rows_k(unsigned char* wsb, size_t st, size_t pt) {
  constexpr int S = 2048;
  unsigned char* ws = wsbase(wsb);
  const f32x4* row = (const f32x4*)((const float*)(ws + st) + (size_t)blockIdx.x * S);
  short4v* out = (short4v*)((short*)(ws + pt) + (size_t)blockIdx.x * S);
  const int tid = threadIdx.x, lane = tid & 63, wv = tid >> 6;
  const f32x4 a = row[tid];
  const f32x4 b = row[tid + 256];
  float m = fmaxf(fmaxf(fmaxf(a[0], a[1]), fmaxf(a[2], a[3])),
                  fmaxf(fmaxf(b[0], b[1]), fmaxf(b[2], b[3])));
#pragma unroll
  for (int o = 32; o; o >>= 1) m = fmaxf(m, __shfl_xor(m, o));
  __shared__ float rb[8];
  if (lane == 0) rb[wv] = m;
  __syncthreads();
  m = fmaxf(fmaxf(rb[0], rb[1]), fmaxf(rb[2], rb[3]));
  float e[8];
  float s = 0.0f;
#pragma unroll
  for (int q = 0; q < 4; ++q) { e[q] = expf(a[q] - m); s += e[q]; }
#pragma unroll
  for (int q = 0; q < 4; ++q) { e[4 + q] = expf(b[q] - m); s += e[4 + q]; }
#pragma unroll
  for (int o = 32; o; o >>= 1) s += __shfl_xor(s, o);
  if (lane == 0) rb[4 + wv] = s;
  __syncthreads();
  s = rb[4] + rb[5] + rb[6] + rb[7];
  const float inv = 1.0f / s;
  short4v o1, o2;
#pragma unroll
  for (int q = 0; q < 4; ++q) { o1[q] = f2bf(e[q] * inv); o2[q] = f2bf(e[4 + q] * inv); }
  out[tid] = o1;
  out[tid + 256] = o2;
}

// ---------------------------------------------------------------------------
extern "C" void kernel_launch(void* const* d_in, const int* in_sizes, int n_in,
                              void* d_out, int out_size, void* d_ws, size_t ws_size,
                              hipStream_t stream) {
  const float* x   = (const float*)d_in[0];
  const float* qw1 = (const float*)d_in[1];
  const float* qb1 = (const float*)d_in[2];
  const float* qw2 = (const float*)d_in[3];
  const float* qb2 = (const float*)d_in[4];
  const float* kw1 = (const float*)d_in[5];
  const float* kb1 = (const float*)d_in[6];
  const float* kw2 = (const float*)d_in[7];
  const float* kb2 = (const float*)d_in[8];
  const float* vw1 = (const float*)d_in[9];
  const float* vb1 = (const float*)d_in[10];
  const float* vw2 = (const float*)d_in[11];
  const float* vb2 = (const float*)d_in[12];
  float* out = (float*)d_out;
  unsigned char* wsb = (ws_size >= WS_TOTAL) ? (unsigned char*)d_ws : nullptr;

  const int M = BB * SS;  // 8192
  dim3 blk(512);
  dim3 tb(32, 8);

  // x -> hi/lo bf16
  split_cast_k<<<4096, 256, 0, stream>>>(x, wsb, OFF_XH, OFF_XL, NX / 4);

  // ---- Q path (split precision) ----
  transpose_cast_k<<<dim3(HHID / 32, DD / 32), tb, 0, stream>>>(qw1, wsb, OFF_WH, OFF_WL, DD, HHID, 1);
  gemm8_k<2, true, 0><<<1024, blk, 0, stream>>>(
      wsb, OFF_XH, OFF_XL, OFF_WH, OFF_WL, qb1, OFF_HH, OFF_HL, nullptr, M, HHID, DD, 32, 1024);
  transpose_cast_k<<<dim3(DD / 32, HHID / 32), tb, 0, stream>>>(qw2, wsb, OFF_WH, OFF_WL, HHID, DD, 1);
  gemm8_k<2, false, 0><<<256, blk, 0, stream>>>(
      wsb, OFF_HH, OFF_HL, OFF_WH, OFF_WL, qb2, OFF_QH, OFF_QL, nullptr, M, DD, HHID, 8, 256);

  // ---- K path (split precision) ----
  transpose_cast_k<<<dim3(HHID / 32, DD / 32), tb, 0, stream>>>(kw1, wsb, OFF_WH, OFF_WL, DD, HHID, 1);
  gemm8_k<2, true, 0><<<1024, blk, 0, stream>>>(
      wsb, OFF_XH, OFF_XL, OFF_WH, OFF_WL, kb1, OFF_HH, OFF_HL, nullptr, M, HHID, DD, 32, 1024);
  transpose_cast_k<<<dim3(DD / 32, HHID / 32), tb, 0, stream>>>(kw2, wsb, OFF_WH, OFF_WL, HHID, DD, 1);
  gemm8_k<2, false, 0><<<256, blk, 0, stream>>>(
      wsb, OFF_HH, OFF_HL, OFF_WH, OFF_WL, kb2, OFF_KH, OFF_KL, nullptr, M, DD, HHID, 8, 256);

  // ---- V path (plain bf16) ----
  transpose_cast_k<<<dim3(HHID / 32, DD / 32), tb, 0, stream>>>(vw1, wsb, OFF_WH, OFF_WL, DD, HHID, 0);
  gemm8_k<1, true, 1><<<1024, blk, 0, stream>>>(
      wsb, OFF_XH, 0, OFF_WH, 0, vb1, OFF_HH, 0, nullptr, M, HHID, DD, 32, 1024);
  transpose_cast_k<<<dim3(DD / 32, HHID / 32), tb, 0, stream>>>(vw2, wsb, OFF_WH, OFF_WL, HHID, DD, 0);
  gemm8_k<1, false, 1><<<256, blk, 0, stream>>>(
      wsb, OFF_HH, 0, OFF_WH, 0, vb2, OFF_V, 0, nullptr, M, DD, HHID, 8, 256);

  // ---- scores^T = (Q K^T)^T per batch, split precision, fp32 ----
  gemm8_k<2, false, 2><<<256, blk, 0, stream>>>(
      wsb, OFF_QH, OFF_QL, OFF_KH, OFF_KL, nullptr, OFF_ST, 0, nullptr, SS, SS, DD, 8, 64);

  // ---- softmax over axis 1 == row softmax of ST; writes bf16 probs^T ----
  softmax_rows_k<<<BB * SS, 256, 0, stream>>>(wsb, OFF_ST, OFF_PT);

  // ---- out = V @ probs  (B^T = probs^T), fp32 to d_out ----
  gemm8_k<1, false, 3><<<256, blk, 0, stream>>>(
      wsb, OFF_V, 0, OFF_PT, 0, nullptr, 0, 0, out, SS, SS, DD, 8, 64);
}